// Round 12
// baseline (641.605 us; speedup 1.0000x reference)
//
#include <hip/hip_runtime.h>
#include <stdint.h>

#define B_ 4
#define S_ 4096
#define D_ 256
#define M_ (B_*S_)  // 16384

typedef __attribute__((ext_vector_type(8))) short bf16x8;
typedef __attribute__((ext_vector_type(8))) unsigned short u16x8;
typedef __attribute__((ext_vector_type(4))) float f32x4;
typedef __attribute__((ext_vector_type(4))) unsigned short u16x4;

static __device__ __forceinline__ unsigned short f2bf(float f) {
  union { float f; unsigned u; } v; v.f = f;
  unsigned r = v.u + 0x7fffu + ((v.u >> 16) & 1u);
  return (unsigned short)(r >> 16);
}
static __device__ __forceinline__ float bf2f(unsigned short h) {
  union { unsigned u; float f; } v; v.u = ((unsigned)h) << 16;
  return v.f;
}

// ---------------- Wq/Wk/Wv -> bf16 in FRAGMENT-LINEAR B-operand layout ----------------
// frag(kc,n) at ushort offset (kc*16+n)*512 + lane*8, holding W[n*16+lr][kc*32+lh*8 .. +7]
__global__ void cvt_w_kernel(const float* __restrict__ Wq, const float* __restrict__ Wk,
                             const float* __restrict__ Wv,
                             unsigned short* __restrict__ wqb, unsigned short* __restrict__ wkb,
                             unsigned short* __restrict__ wvb) {
  const int m = blockIdx.y;
  const float* src = (m == 0) ? Wq : (m == 1) ? Wk : Wv;
  unsigned short* dst = (m == 0) ? wqb : (m == 1) ? wkb : wvb;
  const float scale = (m == 0) ? 0.0625f * 1.44269504f : 1.0f;  // 1/sqrt(256) * log2(e)
  int i = blockIdx.x * 256 + threadIdx.x;  // 8192 chunks of 8 elems
  int frag = i >> 6, lane = i & 63;
  int kc = frag >> 4, n = frag & 15;
  int lr = lane & 15, lh = lane >> 4;
  const float* sp = src + (size_t)(n * 16 + lr) * D_ + kc * 32 + lh * 8;
  float4 a = reinterpret_cast<const float4*>(sp)[0];
  float4 b = reinterpret_cast<const float4*>(sp)[1];
  u16x8 o;
  o[0] = f2bf(a.x * scale); o[1] = f2bf(a.y * scale);
  o[2] = f2bf(a.z * scale); o[3] = f2bf(a.w * scale);
  o[4] = f2bf(b.x * scale); o[5] = f2bf(b.y * scale);
  o[6] = f2bf(b.z * scale); o[7] = f2bf(b.w * scale);
  *reinterpret_cast<u16x8*>(dst + (size_t)frag * 512 + lane * 8) = o;
}

// ---------------- fused QKV projection: y = x @ W^T ----------------
// Reads x as f32 directly (cvt fused). W streamed fragment-linear from L2. No LDS.
// grid (256, 3): bx = 64-row tile. blockIdx.y: 0=q, 1=k, 2=v.
__global__ __launch_bounds__(256, 3) void proj_kernel(
    const float* __restrict__ x,
    const unsigned short* __restrict__ wq,
    const unsigned short* __restrict__ wk,
    const unsigned short* __restrict__ wv,
    unsigned short* __restrict__ q_ws,
    unsigned short* __restrict__ k_ws,
    unsigned short* __restrict__ vt_ws) {
  const int mat = blockIdx.y;
  const unsigned short* wb = (mat == 0) ? wq : (mat == 1) ? wk : wv;
  const int tid = threadIdx.x;
  const int wave = tid >> 6, lane = tid & 63;
  const int lr = lane & 15, lh = lane >> 4;
  const int row0 = blockIdx.x * 64 + wave * 16;

  const f32x4 zero = {0.f, 0.f, 0.f, 0.f};

  bf16x8 af[8];
  {
    const float* xp = x + (size_t)(row0 + lr) * D_ + lh * 8;
    #pragma unroll
    for (int kc = 0; kc < 8; kc++) {
      float4 a = *reinterpret_cast<const float4*>(xp + kc * 32);
      float4 c = *reinterpret_cast<const float4*>(xp + kc * 32 + 4);
      bf16x8 f;
      f[0] = (short)f2bf(a.x); f[1] = (short)f2bf(a.y);
      f[2] = (short)f2bf(a.z); f[3] = (short)f2bf(a.w);
      f[4] = (short)f2bf(c.x); f[5] = (short)f2bf(c.y);
      f[6] = (short)f2bf(c.z); f[7] = (short)f2bf(c.w);
      af[kc] = f;
    }
  }

  f32x4 acc[16];
  #pragma unroll
  for (int n = 0; n < 16; n++) acc[n] = zero;

  #pragma unroll
  for (int kc = 0; kc < 8; kc++) {
    #pragma unroll
    for (int n = 0; n < 16; n++) {
      bf16x8 wf = *reinterpret_cast<const bf16x8*>(wb + (size_t)(kc * 16 + n) * 512 + lane * 8);
      acc[n] = __builtin_amdgcn_mfma_f32_16x16x32_bf16(af[kc], wf, acc[n], 0, 0, 0);
    }
  }

  const int b  = row0 >> 12;
  const int s0 = row0 & 4095;
  const int t2 = s0 >> 5;        // 32-kv tile index (constant per wave)
  const int w1 = wave & 1;       // k-subtile within the 32-kv tile

  if (mat == 0) {
    #pragma unroll
    for (int n = 0; n < 16; n++) {
      int col = n * 16 + lr;
      #pragma unroll
      for (int r = 0; r < 4; r++) {
        int row = row0 + lh * 4 + r;
        q_ws[(size_t)row * D_ + col] = f2bf(acc[n][r]);
      }
    }
  } else if (mat == 1) {
    // K as fragment-linear A-operand tiles (16KB per 32 kv)
    char* tb = reinterpret_cast<char*>(k_ws) + ((size_t)(b * 128 + t2)) * 16384;
    #pragma unroll
    for (int n = 0; n < 16; n++) {
      int base = (w1 * 8 + (n >> 1)) * 1024 +
                 (((n & 1) << 1) | (lr >> 3)) * 256 +
                 lh * 64 + (lr & 7) * 2;
      #pragma unroll
      for (int r = 0; r < 4; r++)
        *reinterpret_cast<unsigned short*>(tb + base + r * 16) = f2bf(acc[n][r]);
    }
  } else {
    // V as fragment-linear B-operand tiles
    char* tb = reinterpret_cast<char*>(vt_ws) + ((size_t)(b * 128 + t2)) * 16384;
    #pragma unroll
    for (int n = 0; n < 16; n++) {
      u16x4 o;
      o.x = f2bf(acc[n][0]); o.y = f2bf(acc[n][1]);
      o.z = f2bf(acc[n][2]); o.w = f2bf(acc[n][3]);
      *reinterpret_cast<u16x4*>(tb + n * 1024 + lh * 256 + lr * 16 + w1 * 8) = o;
    }
  }
}

// ---------------- flash attention: swapped QK^T, split-K=4, 64 q per wave ----------------
// 256 blocks = 8 XCDs x 32; block = 256 q x 1024 kv (quarter). 4 waves x 64 q (4 groups).
// Every kf/vf LDS read feeds 4 q-groups -> half the LDS traffic per unit work vs 32q/wave.
// LDS 64KB dbuf -> 1 block/CU, 4 waves (1/SIMD); VGPR ~460 within 512 budget at 1 wave/EU.
__global__ __launch_bounds__(256, 1) void attn_kernel(
    const unsigned short* __restrict__ q_ws,
    const unsigned short* __restrict__ k_ws,
    const unsigned short* __restrict__ vt_ws,
    unsigned short* __restrict__ po, float* __restrict__ pm, float* __restrict__ pl) {
  __shared__ char lds[2][32768];  // per buf: K tile 16KB | V tile 16KB

  const int bid0 = blockIdx.x;
  const int xcd = bid0 & 7, idx = bid0 >> 3;       // idx in [0,32)
  const int b = xcd >> 1;
  const int h = (xcd & 1) * 2 + (idx >> 4);        // split in [0,4)
  const int qt = idx & 15;
  const int tid = threadIdx.x;
  const int wave = tid >> 6, lane = tid & 63;
  const int lr = lane & 15, lh = lane >> 4;

  const int qrow0 = b * S_ + qt * 256 + wave * 64;

  bf16x8 qf[4][8];
  #pragma unroll
  for (int G = 0; G < 4; G++) {
    const unsigned short* qp = q_ws + (size_t)(qrow0 + G * 16 + lr) * D_ + lh * 8;
    #pragma unroll
    for (int kc = 0; kc < 8; kc++)
      qf[G][kc] = *reinterpret_cast<const bf16x8*>(qp + kc * 32);
  }

  f32x4 oacc[4][16];
  const f32x4 zero = {0.f, 0.f, 0.f, 0.f};
  #pragma unroll
  for (int G = 0; G < 4; G++)
    #pragma unroll
    for (int n = 0; n < 16; n++) oacc[G][n] = zero;
  float m[4], l[4];
  #pragma unroll
  for (int G = 0; G < 4; G++) { m[G] = -1e30f; l[G] = 0.f; }

  const char* kgb = reinterpret_cast<const char*>(k_ws) + ((size_t)(b * 128 + h * 32)) * 16384;
  const char* vgb = reinterpret_cast<const char*>(vt_ws) + ((size_t)(b * 128 + h * 32)) * 16384;

  auto stage = [&](int t, int buf) {
    const char* kg = kgb + (size_t)t * 16384;
    const char* vg = vgb + (size_t)t * 16384;
    char* lk = lds[buf];
    char* lv = lds[buf] + 16384;
    #pragma unroll
    for (int i = 0; i < 4; i++) {
      __builtin_amdgcn_global_load_lds(
        (__attribute__((address_space(1))) void*)(void*)(kg + i * 4096 + tid * 16),
        (__attribute__((address_space(3))) void*)(lk + i * 4096 + tid * 16),
        16, 0, 0);
    }
    #pragma unroll
    for (int i = 0; i < 4; i++) {
      __builtin_amdgcn_global_load_lds(
        (__attribute__((address_space(1))) void*)(void*)(vg + i * 4096 + tid * 16),
        (__attribute__((address_space(3))) void*)(lv + i * 4096 + tid * 16),
        16, 0, 0);
    }
  };

  stage(0, 0);
  __syncthreads();

  for (int t = 0; t < 32; t++) {
    const int cur = t & 1;
    if (t + 1 < 32) stage(t + 1, cur ^ 1);

    const char* lk = lds[cur];
    const char* lv = lds[cur] + 16384;

    // ---- QK^T (swapped): lane owns q = lr; k = half*16 + lh*4 + j ----
    f32x4 s[4][2];
    #pragma unroll
    for (int G = 0; G < 4; G++) { s[G][0] = zero; s[G][1] = zero; }
    __builtin_amdgcn_s_setprio(1);
    #pragma unroll
    for (int kc = 0; kc < 8; kc++) {
      bf16x8 kf0 = *reinterpret_cast<const bf16x8*>(lk + kc * 1024 + lane * 16);
      bf16x8 kf1 = *reinterpret_cast<const bf16x8*>(lk + (8 + kc) * 1024 + lane * 16);
      #pragma unroll
      for (int G = 0; G < 4; G++) {
        s[G][0] = __builtin_amdgcn_mfma_f32_16x16x32_bf16(kf0, qf[G][kc], s[G][0], 0, 0, 0);
        s[G][1] = __builtin_amdgcn_mfma_f32_16x16x32_bf16(kf1, qf[G][kc], s[G][1], 0, 0, 0);
      }
    }
    __builtin_amdgcn_s_setprio(0);

    // ---- in-register online softmax (base-2), defer-max THR=8 ----
    float pmax[4];
    #pragma unroll
    for (int G = 0; G < 4; G++) {
      float mx = fmaxf(fmaxf(fmaxf(s[G][0][0], s[G][0][1]), fmaxf(s[G][0][2], s[G][0][3])),
                       fmaxf(fmaxf(s[G][1][0], s[G][1][1]), fmaxf(s[G][1][2], s[G][1][3])));
      mx = fmaxf(mx, __shfl_xor(mx, 16));
      mx = fmaxf(mx, __shfl_xor(mx, 32));
      pmax[G] = mx;
    }

    int ok = (pmax[0] - m[0] <= 8.f) & (pmax[1] - m[1] <= 8.f) &
             (pmax[2] - m[2] <= 8.f) & (pmax[3] - m[3] <= 8.f);
    if (!__all(ok)) {
      #pragma unroll
      for (int G = 0; G < 4; G++) {
        float mi = fmaxf(m[G], pmax[G]);
        float a = exp2f(m[G] - mi);
        m[G] = mi; l[G] *= a;
        #pragma unroll
        for (int r = 0; r < 4; r++) {
          float av = __shfl(a, lh * 4 + r);
          #pragma unroll
          for (int n = 0; n < 16; n++) oacc[G][n][r] *= av;
        }
      }
    }

    bf16x8 pa[4];
    #pragma unroll
    for (int G = 0; G < 4; G++) {
      float sum = 0.f;
      #pragma unroll
      for (int j = 0; j < 8; j++) {
        float v = (j < 4) ? s[G][0][j & 3] : s[G][1][j & 3];
        float p = exp2f(v - m[G]);
        sum += p;
        pa[G][j] = (short)f2bf(p);
      }
      sum += __shfl_xor(sum, 16);
      sum += __shfl_xor(sum, 32);
      l[G] += sum;
    }

    // ---- PV: each vf read feeds all 4 q-groups ----
    __builtin_amdgcn_s_setprio(1);
    #pragma unroll
    for (int n = 0; n < 16; n++) {
      bf16x8 vf = *reinterpret_cast<const bf16x8*>(lv + n * 1024 + lane * 16);
      #pragma unroll
      for (int G = 0; G < 4; G++)
        oacc[G][n] = __builtin_amdgcn_mfma_f32_16x16x32_bf16(pa[G], vf, oacc[G][n], 0, 0, 0);
    }
    __builtin_amdgcn_s_setprio(0);

    __syncthreads();
  }

  // ---- epilogue: per-wave LDS transpose (own 16KB region), coalesced bf16 stores ----
  __syncthreads();  // make sure all waves finished reading lds before overwrite
  char* pwv = &lds[0][0] + wave * 16384;  // 32 rows x 512B per round
  #pragma unroll
  for (int p = 0; p < 2; p++) {
    #pragma unroll
    for (int g2 = 0; g2 < 2; g2++) {
      int G = p * 2 + g2;
      #pragma unroll
      for (int n = 0; n < 16; n++) {
        int colb = (n * 16 + lr) * 2;
        #pragma unroll
        for (int r = 0; r < 4; r++)
          *reinterpret_cast<unsigned short*>(pwv + (g2 * 16 + lh * 4 + r) * 512 + colb) =
              f2bf(oacc[G][n][r]);
      }
    }
    unsigned short* pob = po + ((size_t)h * 16384 + qrow0 + p * 32) * D_;
    #pragma unroll
    for (int i = 0; i < 16; i++) {
      int off = i * 1024 + lane * 16;
      bf16x8 v = *reinterpret_cast<const bf16x8*>(pwv + off);
      int row = off >> 9, colb = off & 511;
      *reinterpret_cast<bf16x8*>(reinterpret_cast<char*>(pob) + row * 512 + colb) = v;
    }
  }
  #pragma unroll
  for (int G = 0; G < 4; G++) {
    if (lh == G) {
      pm[(size_t)h * 16384 + qrow0 + G * 16 + lr] = m[G];
      pl[(size_t)h * 16384 + qrow0 + G * 16 + lr] = l[G];
    }
  }
}

// ---------------- merge the four KV-splits ----------------
__global__ __launch_bounds__(256) void merge_kernel(
    const unsigned short* __restrict__ po, const float* __restrict__ pm,
    const float* __restrict__ pl, float* __restrict__ out) {
  int idx = blockIdx.x * 256 + threadIdx.x;  // 16384 rows x 32 chunks of 8
  int row = idx >> 5, c8 = idx & 31;
  float m0 = pm[row], m1 = pm[16384 + row], m2 = pm[32768 + row], m3 = pm[49152 + row];
  float l0 = pl[row], l1 = pl[16384 + row], l2 = pl[32768 + row], l3 = pl[49152 + row];
  float M = fmaxf(fmaxf(m0, m1), fmaxf(m2, m3));
  float a0 = exp2f(m0 - M), a1 = exp2f(m1 - M), a2 = exp2f(m2 - M), a3 = exp2f(m3 - M);
  float inv = 1.0f / (l0 * a0 + l1 * a1 + l2 * a2 + l3 * a3);
  float acc[8];
  #pragma unroll
  for (int j = 0; j < 8; j++) acc[j] = 0.f;
  const float aw[4] = {a0, a1, a2, a3};
  #pragma unroll
  for (int hh = 0; hh < 4; hh++) {
    u16x8 v = *reinterpret_cast<const u16x8*>(po + ((size_t)hh * 16384 + row) * D_ + c8 * 8);
    #pragma unroll
    for (int j = 0; j < 8; j++) acc[j] += aw[hh] * bf2f(v[j]);
  }
  float4 o0, o1;
  o0.x = acc[0] * inv; o0.y = acc[1] * inv; o0.z = acc[2] * inv; o0.w = acc[3] * inv;
  o1.x = acc[4] * inv; o1.y = acc[5] * inv; o1.z = acc[6] * inv; o1.w = acc[7] * inv;
  float4* op = reinterpret_cast<float4*>(out + (size_t)row * D_ + c8 * 8);
  op[0] = o0; op[1] = o1;
}

extern "C" void kernel_launch(void* const* d_in, const int* in_sizes, int n_in,
                              void* d_out, int out_size, void* d_ws, size_t ws_size,
                              hipStream_t stream) {
  const float* x  = (const float*)d_in[0];
  const float* Wq = (const float*)d_in[1];
  const float* Wk = (const float*)d_in[2];
  const float* Wv = (const float*)d_in[3];
  float* out = (float*)d_out;

  char* ws = (char*)d_ws;
  unsigned short* wqb   = (unsigned short*)(ws + 8388608);
  unsigned short* wkb   = (unsigned short*)(ws + 8519680);
  unsigned short* wvb   = (unsigned short*)(ws + 8650752);
  unsigned short* q_ws  = (unsigned short*)(ws + 8781824);
  unsigned short* k_ws  = (unsigned short*)(ws + 17170432);
  unsigned short* vt_ws = (unsigned short*)(ws + 25559040);
  unsigned short* po    = (unsigned short*)(ws + 33947648);  // 33.5MB bf16 [4][16384][256]
  float*          pm    = (float*)(ws + 67502080);
  float*          pl    = (float*)(ws + 67764224);

  cvt_w_kernel<<<dim3(32, 3), 256, 0, stream>>>(Wq, Wk, Wv, wqb, wkb, wvb);
  proj_kernel<<<dim3(256, 3), 256, 0, stream>>>(x, wqb, wkb, wvb, q_ws, k_ws, vt_ws);
  attn_kernel<<<256, 256, 0, stream>>>(q_ws, k_ws, vt_ws, po, pm, pl);
  merge_kernel<<<2048, 256, 0, stream>>>(po, pm, pl, out);
}